// Round 1
// baseline (395.952 us; speedup 1.0000x reference)
//
#include <hip/hip_runtime.h>

#define CIN    128
#define COUT   256
#define Hh     112
#define Ww     112
#define HW     12544          // 112*112
#define NBATCH 8
#define NPIX   (NBATCH*HW)    // 100352
#define KD     (CIN*9)        // 1152

typedef __bf16        v8bf __attribute__((ext_vector_type(8)));
typedef float         v4f  __attribute__((ext_vector_type(4)));
typedef unsigned short v8us __attribute__((ext_vector_type(8)));

__device__ __forceinline__ unsigned short f2bf(float f) {
  unsigned int u = __float_as_uint(f);
  u += 0x7FFFu + ((u >> 16) & 1u);   // round-to-nearest-even
  return (unsigned short)(u >> 16);
}

// ---------------------------------------------------------------------------
// Kernel A: xb[b,h,w,c] = bf16(x[b,c,h,w])  (channels-last transpose)
//           sq[b,hw]    = sum_c x^2         (fp32, exact norm base)
// ---------------------------------------------------------------------------
__global__ __launch_bounds__(256) void k_sq_convert(
    const float* __restrict__ x, unsigned short* __restrict__ xb,
    float* __restrict__ sq)
{
  int p = blockIdx.x * 256 + threadIdx.x;     // pixel over B*H*W
  if (p >= NPIX) return;
  int b  = p / HW;
  int hw = p - b * HW;
  const float* xp = x + (size_t)b * CIN * HW + hw;
  unsigned short* xo = xb + (size_t)p * CIN;
  float acc = 0.0f;
  for (int c0 = 0; c0 < CIN; c0 += 8) {
    v8us buf;
#pragma unroll
    for (int j = 0; j < 8; ++j) {
      float v = xp[(size_t)(c0 + j) * HW];    // coalesced across lanes
      acc += v * v;
      buf[j] = f2bf(v);
    }
    *(v8us*)(xo + c0) = buf;                  // 16B store, contiguous per thread
  }
  sq[p] = acc;
}

// ---------------------------------------------------------------------------
// Kernel B: invn[p] = 1 / max(sqrt(3x3 zero-padded box-sum of sq), eps)
// ---------------------------------------------------------------------------
__global__ __launch_bounds__(256) void k_invnorm(
    const float* __restrict__ sq, float* __restrict__ invn)
{
  int p = blockIdx.x * 256 + threadIdx.x;
  if (p >= NPIX) return;
  int b  = p / HW;  int r  = p - b * HW;
  int oy = r / Ww;  int ox = r - oy * Ww;
  const float* s = sq + (size_t)b * HW;
  float acc = 0.0f;
#pragma unroll
  for (int dy = -1; dy <= 1; ++dy) {
    int iy = oy + dy;
    if (iy < 0 || iy >= Hh) continue;
#pragma unroll
    for (int dx = -1; dx <= 1; ++dx) {
      int ix = ox + dx;
      if (ix < 0 || ix >= Ww) continue;
      acc += s[iy * Ww + ix];
    }
  }
  invn[p] = 1.0f / fmaxf(sqrtf(acc), 1e-12f);
}

// ---------------------------------------------------------------------------
// Kernel W: wp[o][(kh*3+kw)*128 + c] = bf16(weight[o][c][kh][kw])
// ---------------------------------------------------------------------------
__global__ __launch_bounds__(256) void k_packw(
    const float* __restrict__ w, unsigned short* __restrict__ wp)
{
  int idx = blockIdx.x * 256 + threadIdx.x;   // < COUT*KD = 294912
  int o  = idx / KD;
  int rr = idx - o * KD;
  int kk = rr >> 7;          // kernel position 0..8
  int c  = rr & 127;
  wp[idx] = f2bf(w[(size_t)o * KD + c * 9 + kk]);
}

// ---------------------------------------------------------------------------
// Kernel C: implicit GEMM  out[n, o] = (sum_d W[o,d] * xb[patch d of n]) * invn[n] + bias[o]
// Block tile 128(M=Cout) x 128(N=pixels); 4 waves as 2x2; wave tile 64x64
// via 4x4 grid of mfma_f32_16x16x32_bf16. K = 9 positions x 128 channels.
// ---------------------------------------------------------------------------
__global__ __launch_bounds__(256, 2) void k_conv(
    const unsigned short* __restrict__ wp,
    const unsigned short* __restrict__ xb,
    const float* __restrict__ invn,
    const float* __restrict__ bias,
    float* __restrict__ out)
{
  int tid  = threadIdx.x;
  int lane = tid & 63;
  int wid  = tid >> 6;
  int wm   = wid >> 1, wn = wid & 1;
  int quad = lane >> 4;
  int l16  = lane & 15;

  int bn = blockIdx.x;   // 0..783  (N tiles of 128 pixels)
  int bm = blockIdx.y;   // 0..1    (M tiles of 128 output channels)

  // A fragment pointers: A[m=l16][k=quad*8+j], contiguous 16B in wp
  const unsigned short* ap[4];
#pragma unroll
  for (int mt = 0; mt < 4; ++mt) {
    int o = bm * 128 + wm * 64 + mt * 16 + l16;
    ap[mt] = wp + (size_t)o * KD + quad * 8;
  }

  // B lane bases (channels-last xb) + per-lane 9-bit validity masks
  long bbase[4];
  int  bval[4];
#pragma unroll
  for (int nt = 0; nt < 4; ++nt) {
    int n  = bn * 128 + wn * 64 + nt * 16 + l16;
    int b  = n / HW;  int r  = n - b * HW;
    int oy = r / Ww;  int ox = r - oy * Ww;
    bbase[nt] = ((long)b * HW + (long)(oy - 1) * Ww + (ox - 1)) * CIN + quad * 8;
    int rm = (oy > 0 ? 1 : 0) | 2 | (oy < Hh - 1 ? 4 : 0);
    int cm = (ox > 0 ? 1 : 0) | 2 | (ox < Ww - 1 ? 4 : 0);
    int m9 = 0;
#pragma unroll
    for (int kh = 0; kh < 3; ++kh)
#pragma unroll
      for (int kw = 0; kw < 3; ++kw)
        if (((rm >> kh) & 1) && ((cm >> kw) & 1)) m9 |= 1 << (kh * 3 + kw);
    bval[nt] = m9;
  }

  v4f acc[4][4];
#pragma unroll
  for (int mt = 0; mt < 4; ++mt)
#pragma unroll
    for (int nt = 0; nt < 4; ++nt)
#pragma unroll
      for (int j = 0; j < 4; ++j) acc[mt][nt][j] = 0.0f;

  v8bf zed;
#pragma unroll
  for (int j = 0; j < 8; ++j) zed[j] = (__bf16)0.0f;

  for (int kh = 0; kh < 3; ++kh) {
    for (int kw = 0; kw < 3; ++kw) {
      int  kkidx = kh * 3 + kw;
      long sh    = (long)(kh * Ww + kw) * CIN;
      bool v[4];
#pragma unroll
      for (int nt = 0; nt < 4; ++nt) v[nt] = (bval[nt] >> kkidx) & 1;
#pragma unroll
      for (int c0 = 0; c0 < CIN; c0 += 32) {
        v8bf a[4], bb[4];
#pragma unroll
        for (int mt = 0; mt < 4; ++mt)
          a[mt] = *(const v8bf*)(ap[mt] + kkidx * CIN + c0);
#pragma unroll
        for (int nt = 0; nt < 4; ++nt)
          bb[nt] = v[nt] ? *(const v8bf*)(xb + bbase[nt] + sh + c0) : zed;
#pragma unroll
        for (int mt = 0; mt < 4; ++mt)
#pragma unroll
          for (int nt = 0; nt < 4; ++nt)
            acc[mt][nt] = __builtin_amdgcn_mfma_f32_16x16x32_bf16(
                a[mt], bb[nt], acc[mt][nt], 0, 0, 0);
      }
    }
  }

  // Epilogue: D col = l16 (pixel), row = quad*4 + reg (output channel)
#pragma unroll
  for (int nt = 0; nt < 4; ++nt) {
    int n = bn * 128 + wn * 64 + nt * 16 + l16;
    float inv = invn[n];
    int b = n / HW;  int r = n - b * HW;
    float* op = out + (size_t)b * COUT * HW + r;
#pragma unroll
    for (int mt = 0; mt < 4; ++mt) {
      int o0 = bm * 128 + wm * 64 + mt * 16 + quad * 4;
#pragma unroll
      for (int reg = 0; reg < 4; ++reg) {
        int o = o0 + reg;
        op[(size_t)o * HW] = acc[mt][nt][reg] * inv + bias[o];
      }
    }
  }
}

// ---------------------------------------------------------------------------
extern "C" void kernel_launch(void* const* d_in, const int* in_sizes, int n_in,
                              void* d_out, int out_size, void* d_ws, size_t ws_size,
                              hipStream_t stream) {
  const float* x    = (const float*)d_in[0];  // [8,128,112,112]
  const float* w    = (const float*)d_in[1];  // [256,128,3,3]
  const float* bias = (const float*)d_in[2];  // [256]
  float* out        = (float*)d_out;          // [8,256,112,112]

  char* ws = (char*)d_ws;
  unsigned short* xb = (unsigned short*)ws;                    // 25,690,112 B
  size_t off = (size_t)NPIX * CIN * 2;
  unsigned short* wpk = (unsigned short*)(ws + off);           // 589,824 B
  off += (size_t)COUT * KD * 2;
  float* sq = (float*)(ws + off);                              // 401,408 B
  off += (size_t)NPIX * 4;
  float* invn = (float*)(ws + off);                            // 401,408 B

  k_sq_convert<<<NPIX / 256, 256, 0, stream>>>(x, xb, sq);
  k_packw<<<(COUT * KD) / 256, 256, 0, stream>>>(w, wpk);
  k_invnorm<<<NPIX / 256, 256, 0, stream>>>(sq, invn);
  k_conv<<<dim3(NPIX / 128, COUT / 128), 256, 0, stream>>>(wpk, xb, invn, bias, out);
}

// Round 2
// 244.442 us; speedup vs baseline: 1.6198x; 1.6198x over previous
//
#include <hip/hip_runtime.h>

#define CIN    128
#define COUT   256
#define Hh     112
#define Ww     112
#define HW     12544          // 112*112
#define NBATCH 8
#define NPIX   (NBATCH*HW)    // 100352
#define KD     (CIN*9)        // 1152
#define PH     114            // padded H/W
#define PPIX   (NBATCH*PH*PH) // padded pixel count

typedef __bf16         v8bf __attribute__((ext_vector_type(8)));
typedef float          v4f  __attribute__((ext_vector_type(4)));
typedef unsigned short v8us __attribute__((ext_vector_type(8)));

__device__ __forceinline__ unsigned short f2bf(float f) {
  unsigned int u = __float_as_uint(f);
  u += 0x7FFFu + ((u >> 16) & 1u);   // round-to-nearest-even
  return (unsigned short)(u >> 16);
}

__device__ __forceinline__ void gl_lds16(const void* g, void* l) {
  __builtin_amdgcn_global_load_lds(
      (const __attribute__((address_space(1))) void*)g,
      (__attribute__((address_space(3))) void*)l, 16, 0, 0);
}

// ---------------------------------------------------------------------------
// Kernel A: xbp[b][oy+1][ox+1][c] = bf16(x[b,c,oy,ox])  (padded channels-last)
//           sq2[half*NPIX + p]    = sum_{c in half} x^2  (fp32)
// One thread per (pixel, channel-half of 64).
// ---------------------------------------------------------------------------
__global__ __launch_bounds__(256) void k_sq_convert(
    const float* __restrict__ x, unsigned short* __restrict__ xbp,
    float* __restrict__ sq2)
{
  int gid  = blockIdx.x * 256 + threadIdx.x;     // < 2*NPIX
  int half = gid >= NPIX ? 1 : 0;
  int p    = gid - half * NPIX;
  int b  = p / HW;
  int hw = p - b * HW;
  int oy = hw / Ww;
  int ox = hw - oy * Ww;
  const float* xp = x + (size_t)b * CIN * HW + hw + (size_t)half * 64 * HW;
  unsigned short* xo = xbp + ((size_t)(b * PH + oy + 1) * PH + (ox + 1)) * CIN + half * 64;
  float acc = 0.0f;
  for (int c0 = 0; c0 < 64; c0 += 8) {
    v8us buf;
#pragma unroll
    for (int j = 0; j < 8; ++j) {
      float v = xp[(size_t)(c0 + j) * HW];       // coalesced across lanes
      acc += v * v;
      buf[j] = f2bf(v);
    }
    *(v8us*)(xo + c0) = buf;
  }
  sq2[(size_t)half * NPIX + p] = acc;
}

// ---------------------------------------------------------------------------
// Kernel Z: zero the 1-pixel border of xbp
// ---------------------------------------------------------------------------
__global__ __launch_bounds__(256) void k_zero_border(unsigned short* __restrict__ xbp)
{
  int gid = blockIdx.x * 256 + threadIdx.x;      // over 8*114*114
  if (gid >= PPIX) return;
  int b  = gid / (PH * PH);
  int r  = gid - b * PH * PH;
  int py = r / PH;
  int px = r - py * PH;
  if (py != 0 && py != PH - 1 && px != 0 && px != PH - 1) return;
  unsigned short* dst = xbp + (size_t)gid * CIN;
  v8us z;
#pragma unroll
  for (int j = 0; j < 8; ++j) z[j] = 0;
#pragma unroll
  for (int c0 = 0; c0 < CIN; c0 += 8) *(v8us*)(dst + c0) = z;
}

// ---------------------------------------------------------------------------
// Kernel B: invn[p] = 1 / max(sqrt(3x3 zero-padded box-sum of sum_c x^2), eps)
// ---------------------------------------------------------------------------
__global__ __launch_bounds__(256) void k_invnorm(
    const float* __restrict__ sq2, float* __restrict__ invn)
{
  int p = blockIdx.x * 256 + threadIdx.x;
  if (p >= NPIX) return;
  int b  = p / HW;  int r  = p - b * HW;
  int oy = r / Ww;  int ox = r - oy * Ww;
  float acc = 0.0f;
#pragma unroll
  for (int dy = -1; dy <= 1; ++dy) {
    int iy = oy + dy;
    if (iy < 0 || iy >= Hh) continue;
#pragma unroll
    for (int dx = -1; dx <= 1; ++dx) {
      int ix = ox + dx;
      if (ix < 0 || ix >= Ww) continue;
      int q = b * HW + iy * Ww + ix;
      acc += sq2[q] + sq2[NPIX + q];
    }
  }
  invn[p] = 1.0f / fmaxf(sqrtf(acc), 1e-12f);
}

// ---------------------------------------------------------------------------
// Kernel W: wp[o][(kh*3+kw)*128 + c] = bf16(weight[o][c][kh][kw])
// ---------------------------------------------------------------------------
__global__ __launch_bounds__(256) void k_packw(
    const float* __restrict__ w, unsigned short* __restrict__ wp)
{
  int idx = blockIdx.x * 256 + threadIdx.x;   // < COUT*KD
  int o  = idx / KD;
  int rr = idx - o * KD;
  int kk = rr >> 7;
  int c  = rr & 127;
  wp[idx] = f2bf(w[(size_t)o * KD + c * 9 + kk]);
}

// ---------------------------------------------------------------------------
// Kernel C: implicit GEMM, m97-style LDS staging.
// Block 128(M=Cout) x 128(N=pixels), BK=64, 18 K-steps (9 pos x 2 c-halves).
// LDS tiles As[row=o][k], Bs[row=n][k], 64 k (128B) per row, 16B chunks
// XOR-swizzled by (row&7) at staging-source time => conflict-free ds_read_b128.
// ---------------------------------------------------------------------------
__global__ __launch_bounds__(256, 3) void k_conv(
    const unsigned short* __restrict__ wp,
    const unsigned short* __restrict__ xbp,
    const float* __restrict__ invn,
    const float* __restrict__ bias,
    float* __restrict__ out)
{
  __shared__ unsigned short As[128 * 64];   // 16 KB
  __shared__ unsigned short Bs[128 * 64];   // 16 KB

  int tid  = threadIdx.x;
  int lane = tid & 63;
  int wid  = tid >> 6;
  int wm   = wid >> 1, wn = wid & 1;
  int quad = lane >> 4;
  int l16  = lane & 15;

  int bn = blockIdx.x;   // N tiles (784)
  int bm = blockIdx.y;   // M tiles (2)

  // --- staging assignment: thread -> (row = tid>>3 (+32 per issue), chunk = tid&7)
  int srow = tid >> 3;                 // 0..31
  int g    = (tid & 7) ^ (srow & 7);   // swizzled source 16B-chunk index

  // A source: wp[(bm*128 + row)*1152 + s*64 + g*8]
  const unsigned short* asrc = wp + (size_t)(bm * 128 + srow) * KD + g * 8;

  // B source: per-row padded pixel base (in shorts), + per-step shift
  int pb[4];
#pragma unroll
  for (int j = 0; j < 4; ++j) {
    int n  = bn * 128 + j * 32 + srow;
    int b  = n / HW;  int r  = n - b * HW;
    int oy = r / Ww;  int ox = r - oy * Ww;
    pb[j] = ((b * PH + oy) * PH + ox) * CIN + g * 8;
  }

  v4f acc[4][4];
#pragma unroll
  for (int mt = 0; mt < 4; ++mt)
#pragma unroll
    for (int nt = 0; nt < 4; ++nt)
#pragma unroll
      for (int j = 0; j < 4; ++j) acc[mt][nt][j] = 0.0f;

  const int khs[9] = {0,0,0,1,1,1,2,2,2};
  const int kws[9] = {0,1,2,0,1,2,0,1,2};

  for (int s = 0; s < 18; ++s) {
    int kk   = s >> 1;
    int c0   = (s & 1) * 64;
    int soff = (khs[kk] * PH + kws[kk]) * CIN + c0;   // shorts

    // stage A tile (16 KB): 4 issues x 256 threads x 16B
#pragma unroll
    for (int j = 0; j < 4; ++j)
      gl_lds16(asrc + (size_t)j * 32 * KD + s * 64,
               &As[(wid * 8 + j * 32) * 64]);
    // stage B tile (16 KB)
#pragma unroll
    for (int j = 0; j < 4; ++j)
      gl_lds16(xbp + pb[j] + soff,
               &Bs[(wid * 8 + j * 32) * 64]);

    __syncthreads();   // vmcnt(0) drain + barrier

#pragma unroll
    for (int h = 0; h < 2; ++h) {            // k0 = h*32
      v8bf af[4], bf[4];
      int cch = (h * 4 + quad) ^ (l16 & 7);  // un-swizzle chunk
#pragma unroll
      for (int mt = 0; mt < 4; ++mt) {
        int m = wm * 64 + mt * 16 + l16;
        af[mt] = *(const v8bf*)&As[m * 64 + cch * 8];
      }
#pragma unroll
      for (int nt = 0; nt < 4; ++nt) {
        int nr = wn * 64 + nt * 16 + l16;
        bf[nt] = *(const v8bf*)&Bs[nr * 64 + cch * 8];
      }
#pragma unroll
      for (int mt = 0; mt < 4; ++mt)
#pragma unroll
        for (int nt = 0; nt < 4; ++nt)
          acc[mt][nt] = __builtin_amdgcn_mfma_f32_16x16x32_bf16(
              af[mt], bf[nt], acc[mt][nt], 0, 0, 0);
    }

    __syncthreads();   // protect LDS from next step's staging
  }

  // Epilogue: D col = l16 (pixel), row = quad*4 + reg (output channel)
#pragma unroll
  for (int nt = 0; nt < 4; ++nt) {
    int n = bn * 128 + wn * 64 + nt * 16 + l16;
    float inv = invn[n];
    int b = n / HW;  int r = n - b * HW;
    float* op = out + (size_t)b * COUT * HW + r;
#pragma unroll
    for (int mt = 0; mt < 4; ++mt) {
      int o0 = bm * 128 + wm * 64 + mt * 16 + quad * 4;
#pragma unroll
      for (int reg = 0; reg < 4; ++reg) {
        int o = o0 + reg;
        op[(size_t)o * HW] = acc[mt][nt][reg] * inv + bias[o];
      }
    }
  }
}

// ---------------------------------------------------------------------------
extern "C" void kernel_launch(void* const* d_in, const int* in_sizes, int n_in,
                              void* d_out, int out_size, void* d_ws, size_t ws_size,
                              hipStream_t stream) {
  const float* x    = (const float*)d_in[0];  // [8,128,112,112]
  const float* w    = (const float*)d_in[1];  // [256,128,3,3]
  const float* bias = (const float*)d_in[2];  // [256]
  float* out        = (float*)d_out;          // [8,256,112,112]

  char* ws = (char*)d_ws;
  unsigned short* xbp = (unsigned short*)ws;                   // 26,615,808 B
  size_t off = (size_t)PPIX * CIN * 2;
  unsigned short* wpk = (unsigned short*)(ws + off);           // 589,824 B
  off += (size_t)COUT * KD * 2;
  float* sq2 = (float*)(ws + off);                             // 802,816 B
  off += (size_t)2 * NPIX * 4;
  float* invn = (float*)(ws + off);                            // 401,408 B

  k_sq_convert<<<2 * NPIX / 256, 256, 0, stream>>>(x, xbp, sq2);
  k_zero_border<<<(PPIX + 255) / 256, 256, 0, stream>>>(xbp);
  k_packw<<<(COUT * KD) / 256, 256, 0, stream>>>(w, wpk);
  k_invnorm<<<NPIX / 256, 256, 0, stream>>>(sq2, invn);
  k_conv<<<dim3(NPIX / 128, COUT / 128), 256, 0, stream>>>(wpk, xbp, invn, bias, out);
}

// Round 3
// 216.227 us; speedup vs baseline: 1.8312x; 1.1305x over previous
//
#include <hip/hip_runtime.h>

#define CIN    128
#define COUT   256
#define Hh     112
#define Ww     112
#define HW     12544          // 112*112
#define NBATCH 8
#define NPIX   (NBATCH*HW)    // 100352
#define KD     (CIN*9)        // 1152
#define PH     114            // padded H/W
#define PPIX   (NBATCH*PH*PH) // padded pixel count

typedef __bf16         v8bf __attribute__((ext_vector_type(8)));
typedef float          v4f  __attribute__((ext_vector_type(4)));

__device__ __forceinline__ unsigned short f2bf(float f) {
  unsigned int u = __float_as_uint(f);
  u += 0x7FFFu + ((u >> 16) & 1u);   // round-to-nearest-even
  return (unsigned short)(u >> 16);
}

__device__ __forceinline__ void gl_lds16(const void* g, void* l) {
  __builtin_amdgcn_global_load_lds(
      (const __attribute__((address_space(1))) void*)g,
      (__attribute__((address_space(3))) void*)l, 16, 0, 0);
}

// ---------------------------------------------------------------------------
// Kernel A: padded channels-last bf16 transpose + per-pixel sum(x^2), via LDS.
// One block = 56 pixels (half a row) x 128 channels. Coalesced both directions.
// ---------------------------------------------------------------------------
#define SQS 65   // uint-stride of LDS pixel row (64 + 1 pad)
__global__ __launch_bounds__(256) void k_sq_convert(
    const float* __restrict__ x, unsigned short* __restrict__ xbp,
    float* __restrict__ sq)
{
  __shared__ unsigned int US[56 * SQS];   // 14,560 B
  __shared__ float sqp[56 * 4];

  int tid = threadIdx.x;
  int l   = tid & 63;
  int wid = tid >> 6;
  int bid = blockIdx.x;          // 8 * 112 * 2
  int xh  = bid & 1;
  int t2  = bid >> 1;
  int b   = t2 / Hh;
  int oy  = t2 - b * Hh;
  int ox0 = xh * 56;

  const float* xp = x + (size_t)b * CIN * HW + oy * Ww + ox0;
  bool valid = l < 56;
  float acc = 0.0f;
#pragma unroll
  for (int it = 0; it < 16; ++it) {
    int cp = it * 4 + wid;       // channel-pair 0..63
    int c0 = cp * 2;
    float v0 = 0.0f, v1 = 0.0f;
    if (valid) {
      v0 = xp[(size_t)c0 * HW + l];        // 56 consecutive floats per instr
      v1 = xp[(size_t)(c0 + 1) * HW + l];
    }
    acc += v0 * v0 + v1 * v1;
    unsigned int pk = (unsigned int)f2bf(v0) | ((unsigned int)f2bf(v1) << 16);
    if (valid) US[l * SQS + cp] = pk;      // (l+cp)%32 banks: 2-way max
  }
  if (valid) sqp[l * 4 + wid] = acc;
  __syncthreads();

  if (tid < 56) {
    float s = sqp[tid * 4] + sqp[tid * 4 + 1] + sqp[tid * 4 + 2] + sqp[tid * 4 + 3];
    sq[(size_t)b * HW + oy * Ww + ox0 + tid] = s;
  }

  // store: 56 pixels x 64 uints contiguous in xbp (consecutive px, one row)
  unsigned int* dst = (unsigned int*)xbp +
      ((size_t)(b * PH + oy + 1) * PH + (ox0 + 1)) * (CIN / 2);
  for (int h = tid; h < 896; h += 256) {   // 896 chunks of 16B
    int u0  = h * 4;
    int pix = u0 >> 6, cu = u0 & 63;
    const unsigned int* s = &US[pix * SQS + cu];
    uint4 vv; vv.x = s[0]; vv.y = s[1]; vv.z = s[2]; vv.w = s[3];
    *(uint4*)(dst + u0) = vv;              // fully coalesced across lanes
  }
}

// ---------------------------------------------------------------------------
// Kernel Z: zero the 1-pixel border of xbp
// ---------------------------------------------------------------------------
__global__ __launch_bounds__(256) void k_zero_border(unsigned short* __restrict__ xbp)
{
  int gid = blockIdx.x * 256 + threadIdx.x;
  if (gid >= PPIX) return;
  int b  = gid / (PH * PH);
  int r  = gid - b * PH * PH;
  int py = r / PH;
  int px = r - py * PH;
  if (py != 0 && py != PH - 1 && px != 0 && px != PH - 1) return;
  unsigned int* dst = (unsigned int*)xbp + (size_t)gid * (CIN / 2);
  uint4 z = {0, 0, 0, 0};
#pragma unroll
  for (int c0 = 0; c0 < 64; c0 += 4) *(uint4*)(dst + c0) = z;
}

// ---------------------------------------------------------------------------
// Kernel B: invn[p] = 1 / max(sqrt(3x3 zero-padded box-sum of sq), eps)
// ---------------------------------------------------------------------------
__global__ __launch_bounds__(256) void k_invnorm(
    const float* __restrict__ sq, float* __restrict__ invn)
{
  int p = blockIdx.x * 256 + threadIdx.x;
  if (p >= NPIX) return;
  int b  = p / HW;  int r  = p - b * HW;
  int oy = r / Ww;  int ox = r - oy * Ww;
  const float* s = sq + (size_t)b * HW;
  float acc = 0.0f;
#pragma unroll
  for (int dy = -1; dy <= 1; ++dy) {
    int iy = oy + dy;
    if (iy < 0 || iy >= Hh) continue;
#pragma unroll
    for (int dx = -1; dx <= 1; ++dx) {
      int ix = ox + dx;
      if (ix < 0 || ix >= Ww) continue;
      acc += s[iy * Ww + ix];
    }
  }
  invn[p] = 1.0f / fmaxf(sqrtf(acc), 1e-12f);
}

// ---------------------------------------------------------------------------
// Kernel W: wp[o][(kh*3+kw)*128 + c] = bf16(weight[o][c][kh][kw])
// ---------------------------------------------------------------------------
__global__ __launch_bounds__(256) void k_packw(
    const float* __restrict__ w, unsigned short* __restrict__ wp)
{
  int idx = blockIdx.x * 256 + threadIdx.x;
  int o  = idx / KD;
  int rr = idx - o * KD;
  int kk = rr >> 7;
  int c  = rr & 127;
  wp[idx] = f2bf(w[(size_t)o * KD + c * 9 + kk]);
}

// ---------------------------------------------------------------------------
// Kernel C: implicit GEMM, LDS staging via global_load_lds(16B), BK=64,
// 128x128 tile, 18 K-steps. Epilogue through padded LDS slab for fully
// coalesced output stores. Grid: 1568 linear blocks, XCD-paired swizzle.
// ---------------------------------------------------------------------------
#define SLAB_S 132   // fp32 slab stride: 16B-aligned rows, 2-way banks max
__global__ __launch_bounds__(256, 3) void k_conv(
    const unsigned short* __restrict__ wp,
    const unsigned short* __restrict__ xbp,
    const float* __restrict__ invn,
    const float* __restrict__ bias,
    float* __restrict__ out)
{
  __shared__ __align__(16) char smem[64 * SLAB_S * 4];   // 33,792 B
  unsigned short* As = (unsigned short*)smem;            // [128][64]
  unsigned short* Bs = As + 128 * 64;                    // [128][64]
  float* slab = (float*)smem;                            // [64][SLAB_S]

  int tid  = threadIdx.x;
  int lane = tid & 63;
  int wid  = tid >> 6;
  int wm   = wid >> 1, wn = wid & 1;
  int quad = lane >> 4;
  int l16  = lane & 15;

  // XCD-paired swizzle: both bm of one bn land on the same XCD (adjacent %8)
  int L  = blockIdx.x;           // 0..1567
  int g  = L >> 4;
  int j  = L & 15;
  int bn = g * 8 + (j & 7);      // 0..783
  int bm = j >> 3;               // 0..1

  // staging: thread -> (row = tid>>3 (+32/issue), chunk = (tid&7) XOR-swizzled)
  int srow = tid >> 3;
  int g16  = (tid & 7) ^ (srow & 7);

  const unsigned short* asrc = wp + (size_t)(bm * 128 + srow) * KD + g16 * 8;

  int pb[4];
#pragma unroll
  for (int jj = 0; jj < 4; ++jj) {
    int n  = bn * 128 + jj * 32 + srow;
    int b  = n / HW;  int r  = n - b * HW;
    int oy = r / Ww;  int ox = r - oy * Ww;
    pb[jj] = ((b * PH + oy) * PH + ox) * CIN + g16 * 8;
  }

  v4f acc[4][4];
#pragma unroll
  for (int mt = 0; mt < 4; ++mt)
#pragma unroll
    for (int nt = 0; nt < 4; ++nt)
#pragma unroll
      for (int q = 0; q < 4; ++q) acc[mt][nt][q] = 0.0f;

  const int khs[9] = {0,0,0,1,1,1,2,2,2};
  const int kws[9] = {0,1,2,0,1,2,0,1,2};

  for (int s = 0; s < 18; ++s) {
    int kk   = s >> 1;
    int c0   = (s & 1) * 64;
    int soff = (khs[kk] * PH + kws[kk]) * CIN + c0;

#pragma unroll
    for (int jj = 0; jj < 4; ++jj)
      gl_lds16(asrc + (size_t)jj * 32 * KD + s * 64,
               &As[(wid * 8 + jj * 32) * 64]);
#pragma unroll
    for (int jj = 0; jj < 4; ++jj)
      gl_lds16(xbp + pb[jj] + soff,
               &Bs[(wid * 8 + jj * 32) * 64]);

    __syncthreads();

#pragma unroll
    for (int h = 0; h < 2; ++h) {
      v8bf af[4], bf[4];
      int cch = (h * 4 + quad) ^ (l16 & 7);
#pragma unroll
      for (int mt = 0; mt < 4; ++mt)
        af[mt] = *(const v8bf*)&As[(wm * 64 + mt * 16 + l16) * 64 + cch * 8];
#pragma unroll
      for (int nt = 0; nt < 4; ++nt)
        bf[nt] = *(const v8bf*)&Bs[(wn * 64 + nt * 16 + l16) * 64 + cch * 8];
#pragma unroll
      for (int mt = 0; mt < 4; ++mt)
#pragma unroll
        for (int nt = 0; nt < 4; ++nt)
          acc[mt][nt] = __builtin_amdgcn_mfma_f32_16x16x32_bf16(
              af[mt], bf[nt], acc[mt][nt], 0, 0, 0);
    }

    __syncthreads();
  }

  // ------------- epilogue: LDS slab transpose -> coalesced row stores -----
  int nbase = bn * 128;
  int bb = nbase / HW;           // 128 | HW, tile within one batch
  int rr = nbase - bb * HW;
  float* obase = out + (size_t)bb * COUT * HW + rr;

  float invv[4];
#pragma unroll
  for (int nt = 0; nt < 4; ++nt)
    invv[nt] = invn[nbase + wn * 64 + nt * 16 + l16];

  for (int pass = 0; pass < 2; ++pass) {
    if (pass) __syncthreads();
    if (wm == pass) {
#pragma unroll
      for (int mt = 0; mt < 4; ++mt)
#pragma unroll
        for (int nt = 0; nt < 4; ++nt) {
          int col = wn * 64 + nt * 16 + l16;
#pragma unroll
          for (int reg = 0; reg < 4; ++reg)
            slab[(mt * 16 + quad * 4 + reg) * SLAB_S + col] =
                acc[mt][nt][reg] * invv[nt];
        }
    }
    __syncthreads();
#pragma unroll
    for (int it = 0; it < 2; ++it) {
      int row = it * 32 + (tid >> 3);
      int o   = bm * 128 + pass * 64 + row;
      float bv = bias[o];
      float* orow = obase + (size_t)o * HW;
#pragma unroll
      for (int k = 0; k < 4; ++k) {
        int c4 = ((tid & 7) + k * 8) * 4;
        v4f v = *(const v4f*)&slab[row * SLAB_S + c4];
        v4f r2;
#pragma unroll
        for (int q = 0; q < 4; ++q) r2[q] = v[q] + bv;
        *(v4f*)(orow + c4) = r2;           // 8 lanes -> 128B contiguous
      }
    }
  }
}

// ---------------------------------------------------------------------------
extern "C" void kernel_launch(void* const* d_in, const int* in_sizes, int n_in,
                              void* d_out, int out_size, void* d_ws, size_t ws_size,
                              hipStream_t stream) {
  const float* x    = (const float*)d_in[0];  // [8,128,112,112]
  const float* w    = (const float*)d_in[1];  // [256,128,3,3]
  const float* bias = (const float*)d_in[2];  // [256]
  float* out        = (float*)d_out;          // [8,256,112,112]

  char* ws = (char*)d_ws;
  unsigned short* xbp = (unsigned short*)ws;                   // 26,615,808 B
  size_t off = (size_t)PPIX * CIN * 2;
  unsigned short* wpk = (unsigned short*)(ws + off);           // 589,824 B
  off += (size_t)COUT * KD * 2;
  float* sq = (float*)(ws + off);                              // 401,408 B
  off += (size_t)NPIX * 4;
  float* invn = (float*)(ws + off);                            // 401,408 B

  k_sq_convert<<<NBATCH * Hh * 2, 256, 0, stream>>>(x, xbp, sq);
  k_zero_border<<<(PPIX + 255) / 256, 256, 0, stream>>>(xbp);
  k_packw<<<(COUT * KD) / 256, 256, 0, stream>>>(w, wpk);
  k_invnorm<<<NPIX / 256, 256, 0, stream>>>(sq, invn);
  k_conv<<<1568, 256, 0, stream>>>(wpk, xbp, invn, bias, out);
}